// Round 6
// baseline (58.251 us; speedup 1.0000x reference)
//
#include <hip/hip_runtime.h>
#include <stdint.h>
#include <math.h>

typedef __attribute__((ext_vector_type(8))) short short8;
typedef __attribute__((ext_vector_type(16))) float f32x16;

#define DEVI static __device__ __forceinline__

constexpr int D = 256;  // feature dim

// ws layout (bytes)
constexpr size_t WS_EIMG  = 0;                   // 16 tiles x 16384 = 262144
constexpr size_t WS_ETERM = 262144;              // 512 f32
constexpr size_t WS_WMAX  = 264192;              // 512 blk x 512 col f32 = 1 MB
constexpr size_t WS_WSUM  = WS_WMAX + 1048576;   // 1 MB
constexpr size_t WS_PART  = WS_WSUM + 1048576;   // 128 f32

DEVI unsigned int f2bf(float f) {
  unsigned int u = __float_as_uint(f);
  return (u + 0x7fffu + ((u >> 16) & 1u)) >> 16;  // RNE f32->bf16 (finite)
}
DEVI float shflx(float v, int m) { return __shfl_xor(v, m, 64); }

// ---- prep: e -> wave-coalesced B-fragment images + eterm ----
// Tile t covers cols [t*32, t*32+32). Fragment for k-step s, lane (hi,c):
//   byte = t*16384 + s*1024 + (hi*32 + c)*16   holding granule g = 2s+hi
//   (k in [g*8, g*8+8)) of col c, as 8 bf16 of a*e.
// 16 blocks x 256 thr; thread = (col c = t>>3, octant o = t&7).
__global__ void prep_e(const float* __restrict__ e, const float* __restrict__ lsp,
                       char* __restrict__ eimg, float* __restrict__ eterm) {
  const int et = blockIdx.x, t = threadIdx.x;
  const int c = t >> 3, o = t & 7;   // col in tile, octant of 256 k
  const int gc = et * 32 + c;
  const float a = __expf(-2.0f * lsp[0]);
  const float* s = e + (size_t)gc * D + o * 32;
  float sq = 0.0f;
  unsigned int w[16];
#pragma unroll
  for (int i = 0; i < 8; ++i) {
    float4 x = *(const float4*)(s + i * 4);
    sq += x.x * x.x + x.y * x.y + x.z * x.z + x.w * x.w;
    w[2 * i]     = f2bf(a * x.x) | (f2bf(a * x.y) << 16);
    w[2 * i + 1] = f2bf(a * x.z) | (f2bf(a * x.w) << 16);
  }
  sq += shflx(sq, 1); sq += shflx(sq, 2); sq += shflx(sq, 4);  // 8-lane group
  char* base = eimg + (size_t)et * 16384;
#pragma unroll
  for (int i = 0; i < 4; ++i) {
    int g = o * 4 + i;  // global 16B k-granule
    int phys = (g >> 1) * 1024 + (g & 1) * 512 + c * 16;
    uint4 pk; pk.x = w[4 * i]; pk.y = w[4 * i + 1];
    pk.z = w[4 * i + 2]; pk.w = w[4 * i + 3];
    *(uint4*)(base + phys) = pk;
  }
  if (o == 0) eterm[gc] = -0.5f * a * sq;
}

// ---- main: 512 blocks x 256 thr (4 waves). Wave owns 32 z-rows resident in
// A-fragments; B read straight from L2-resident eimg (coalesced 1KB/load).
// NO barriers / NO LDS in the phase loop; one __syncthreads at the end. ----
__global__ __launch_bounds__(256, 2)
void lse_main(const float* __restrict__ z, const char* __restrict__ eimg,
              const float* __restrict__ lsp, float* __restrict__ wmax,
              float* __restrict__ wsum) {
  __shared__ float sh_m[4][512];
  __shared__ float sh_s[4][512];

  const int tid = threadIdx.x;
  const int wid = tid >> 6, lane = tid & 63;
  const int l31 = lane & 31;   // A row within wave / C col (e-col)
  const int hi  = lane >> 5;   // k-half of A/B frag; C row-group bit
  const int bx = blockIdx.x;
  const float a = __expf(-2.0f * lsp[0]);

  // z -> A fragments (32x32x16 layout): lane holds row bx*128 + wid*32 + l31,
  // k = s*16 + hi*8 + j. Fenced groups of 2 steps keep load-reg pressure low.
  short8 A[16];
  const float* zs = z + ((size_t)bx * 128 + wid * 32 + l31) * D + hi * 8;
  float sq = 0.0f;
#pragma unroll
  for (int g = 0; g < 8; ++g) {
#pragma unroll
    for (int s2 = 0; s2 < 2; ++s2) {
      const int s = g * 2 + s2;
      float4 x0 = *(const float4*)(zs + s * 16);
      float4 x1 = *(const float4*)(zs + s * 16 + 4);
      sq += x0.x * x0.x + x0.y * x0.y + x0.z * x0.z + x0.w * x0.w +
            x1.x * x1.x + x1.y * x1.y + x1.z * x1.z + x1.w * x1.w;
      uint4 pk;
      pk.x = f2bf(x0.x) | (f2bf(x0.y) << 16);
      pk.y = f2bf(x0.z) | (f2bf(x0.w) << 16);
      pk.z = f2bf(x1.x) | (f2bf(x1.y) << 16);
      pk.w = f2bf(x1.z) | (f2bf(x1.w) << 16);
      A[s] = __builtin_bit_cast(short8, pk);
    }
    asm volatile("" ::: "memory");
  }
  sq += shflx(sq, 32);  // partner lane holds the other k-half of the same row
  const float term = -0.5f * a * sq;  // valid in lanes l31 (row) and l31+32

  // zterm for this lane's 16 C-rows via in-wave broadcast (no LDS):
  // C row = (r&3) + 8*(r>>2) + 4*hi; lane 'row' (0..31) holds that row's term.
  float zt[16];
#pragma unroll
  for (int r = 0; r < 16; ++r)
    zt[r] = __shfl(term, (r & 3) + 8 * (r >> 2) + 4 * hi, 64);

  for (int p = 0; p < 8; ++p) {
    const char* t0 = eimg + (size_t)(2 * p) * 16384 + lane * 16;
    const char* t1 = t0 + 16384;

    f32x16 acc0, acc1;
#pragma unroll
    for (int i = 0; i < 16; ++i) { acc0[i] = 0.0f; acc1[i] = 0.0f; }
#pragma unroll
    for (int s = 0; s < 16; ++s) {
      short8 B0 = *(const short8*)(t0 + s * 1024);
      short8 B1 = *(const short8*)(t1 + s * 1024);
      acc0 = __builtin_amdgcn_mfma_f32_32x32x16_bf16(A[s], B0, acc0, 0, 0, 0);
      acc1 = __builtin_amdgcn_mfma_f32_32x32x16_bf16(A[s], B1, acc1, 0, 0, 0);
    }

    // epilogue (wave-local): lane has cols (p*64 + l31) and (p*64 + 32 + l31),
    // 16 z-rows each. LSE partials over the wave's 32 rows.
    float mx0 = -1e30f, mx1 = -1e30f;
#pragma unroll
    for (int r = 0; r < 16; ++r) {
      acc0[r] += zt[r]; acc1[r] += zt[r];
      mx0 = fmaxf(mx0, acc0[r]); mx1 = fmaxf(mx1, acc1[r]);
    }
    mx0 = fmaxf(mx0, shflx(mx0, 32));  // other 16 rows live in partner lane
    mx1 = fmaxf(mx1, shflx(mx1, 32));
    float sm0 = 0.0f, sm1 = 0.0f;
#pragma unroll
    for (int r = 0; r < 16; ++r) {
      sm0 += __expf(acc0[r] - mx0);
      sm1 += __expf(acc1[r] - mx1);
    }
    sm0 += shflx(sm0, 32);
    sm1 += shflx(sm1, 32);
    if (hi == 0) {
      sh_m[wid][p * 64 + l31] = mx0;      sh_s[wid][p * 64 + l31] = sm0;
      sh_m[wid][p * 64 + 32 + l31] = mx1; sh_s[wid][p * 64 + 32 + l31] = sm1;
    }
  }

  __syncthreads();  // the ONLY block-wide barrier

  // merge 4 waves -> 128-row block partial for each of 512 cols
#pragma unroll
  for (int h = 0; h < 2; ++h) {
    const int c = h * 256 + tid;
    float m0 = sh_m[0][c], m1 = sh_m[1][c], m2 = sh_m[2][c], m3 = sh_m[3][c];
    float nm = fmaxf(fmaxf(m0, m1), fmaxf(m2, m3));
    float s = sh_s[0][c] * __expf(m0 - nm) + sh_s[1][c] * __expf(m1 - nm) +
              sh_s[2][c] * __expf(m2 - nm) + sh_s[3][c] * __expf(m3 - nm);
    wmax[(size_t)bx * 512 + c] = nm;
    wsum[(size_t)bx * 512 + c] = s;
  }
}

// ---- merge 4 main-blocks per 512-row b-block, add eterm, sum over cols ----
__global__ void merge_b(const float* __restrict__ wmax, const float* __restrict__ wsum,
                        const float* __restrict__ eterm, float* __restrict__ partial) {
  __shared__ float sh[512];
  const int b = blockIdx.x, t = threadIdx.x;
  float m[4];
  float nm = -1e30f;
#pragma unroll
  for (int i = 0; i < 4; ++i) {
    m[i] = wmax[(size_t)(4 * b + i) * 512 + t];
    nm = fmaxf(nm, m[i]);
  }
  float s = 0.0f;
#pragma unroll
  for (int i = 0; i < 4; ++i)
    s += wsum[(size_t)(4 * b + i) * 512 + t] * __expf(m[i] - nm);
  sh[t] = nm + logf(s) + eterm[t];
  __syncthreads();
  for (int st = 256; st > 0; st >>= 1) {
    if (t < st) sh[t] += sh[t + st];
    __syncthreads();
  }
  if (t == 0) partial[b] = sh[0];
}

__global__ void final_k(const float* __restrict__ partial,
                        const float* __restrict__ lsp, float* __restrict__ out) {
  __shared__ float sh[128];
  const int t = threadIdx.x;
  sh[t] = partial[t];
  __syncthreads();
  for (int st = 64; st > 0; st >>= 1) {
    if (t < st) sh[t] += sh[t + st];
    __syncthreads();
  }
  if (t == 0) {
    float ls = lsp[0];
    out[0] = -sh[0] / 65536.0f + 128.0f * (2.0f * ls - 1.0f) + logf(512.0f);
  }
}

extern "C" void kernel_launch(void* const* d_in, const int* in_sizes, int n_in,
                              void* d_out, int out_size, void* d_ws, size_t ws_size,
                              hipStream_t stream) {
  const float* z   = (const float*)d_in[0];
  const float* e   = (const float*)d_in[1];
  const float* lsp = (const float*)d_in[2];
  float* out = (float*)d_out;
  char* ws = (char*)d_ws;
  char*  eimg    = ws + WS_EIMG;
  float* eterm   = (float*)(ws + WS_ETERM);
  float* wmax    = (float*)(ws + WS_WMAX);
  float* wsum    = (float*)(ws + WS_WSUM);
  float* partial = (float*)(ws + WS_PART);

  prep_e<<<dim3(16), dim3(256), 0, stream>>>(e, lsp, eimg, eterm);
  lse_main<<<dim3(512), dim3(256), 0, stream>>>(z, eimg, lsp, wmax, wsum);
  merge_b<<<dim3(128), dim3(512), 0, stream>>>(wmax, wsum, eterm, partial);
  final_k<<<dim3(1), dim3(128), 0, stream>>>(partial, lsp, out);
}

// Round 7
// 48.892 us; speedup vs baseline: 1.1914x; 1.1914x over previous
//
#include <hip/hip_runtime.h>
#include <stdint.h>
#include <math.h>

typedef __attribute__((ext_vector_type(8))) short short8;
typedef __attribute__((ext_vector_type(16))) float f32x16;

#define DEVI static __device__ __forceinline__

constexpr int D = 256;  // feature dim

// ws layout (bytes)
constexpr size_t WS_EIMG  = 0;                   // 16 tiles x 16384 = 262144
constexpr size_t WS_ETERM = 262144;              // 512 f32
constexpr size_t WS_WMAX  = 264192;              // 256 blk x 512 col f32 = 512K
constexpr size_t WS_WSUM  = WS_WMAX + 524288;    // 512K
constexpr size_t WS_PART  = WS_WSUM + 524288;    // 128 f32

DEVI unsigned int f2bf(float f) {
  unsigned int u = __float_as_uint(f);
  return (u + 0x7fffu + ((u >> 16) & 1u)) >> 16;  // RNE f32->bf16 (finite)
}
DEVI float shflx(float v, int m) { return __shfl_xor(v, m, 64); }

// ---- prep: e -> wave-coalesced A-fragment images + eterm ----
// Tile w covers cols [w*32, w*32+32). Fragment for k-step s, lane (hi,m):
//   byte = w*16384 + s*1024 + (hi*32 + m)*16 holds granule g = 2s+hi
//   (k in [g*8, g*8+8)) of col m, as 8 bf16 of a*e.
__global__ void prep_e(const float* __restrict__ e, const float* __restrict__ lsp,
                       char* __restrict__ eimg, float* __restrict__ eterm) {
  const int et = blockIdx.x, t = threadIdx.x;
  const int c = t >> 3, o = t & 7;   // col in tile, octant of 256 k
  const int gc = et * 32 + c;
  const float a = __expf(-2.0f * lsp[0]);
  const float* s = e + (size_t)gc * D + o * 32;
  float sq = 0.0f;
  unsigned int w[16];
#pragma unroll
  for (int i = 0; i < 8; ++i) {
    float4 x = *(const float4*)(s + i * 4);
    sq += x.x * x.x + x.y * x.y + x.z * x.z + x.w * x.w;
    w[2 * i]     = f2bf(a * x.x) | (f2bf(a * x.y) << 16);
    w[2 * i + 1] = f2bf(a * x.z) | (f2bf(a * x.w) << 16);
  }
  sq += shflx(sq, 1); sq += shflx(sq, 2); sq += shflx(sq, 4);  // 8-lane group
  char* base = eimg + (size_t)et * 16384;
#pragma unroll
  for (int i = 0; i < 4; ++i) {
    int g = o * 4 + i;  // global 16B k-granule
    int phys = (g >> 1) * 1024 + (g & 1) * 512 + c * 16;
    uint4 pk; pk.x = w[4 * i]; pk.y = w[4 * i + 1];
    pk.z = w[4 * i + 2]; pk.w = w[4 * i + 3];
    *(uint4*)(base + phys) = pk;
  }
  if (o == 0) eterm[gc] = -0.5f * a * sq;
}

// ---- main: 256 blocks x 1024 thr (16 waves, 1 block/CU, 4 waves/SIMD).
// Wave w holds e-cols [32w,32w+32) resident as A-frags; block streams its 256
// z-rows in 8 chunks of 32 through double-buffered LDS. Running LSE state is
// per-lane (lane = z-row slot, regs = 16 e-cols). One barrier per chunk. ----
__global__ __launch_bounds__(1024, 4)
void lse_main(const float* __restrict__ z, const char* __restrict__ eimg,
              const float* __restrict__ lsp, float* __restrict__ wmax,
              float* __restrict__ wsum) {
  __shared__ char  zbuf[2][16384];
  __shared__ float ztm[2][32];

  const int tid = threadIdx.x;
  const int wid = tid >> 6, lane = tid & 63;
  const int l31 = lane & 31;   // z-row slot (C col) / A col within tile
  const int hi  = lane >> 5;   // k-half of frags; C row-group bit
  const int n_st = tid >> 5;   // staging: chunk-local z-row 0..31
  const int g_st = tid & 31;   // staging: 16B bf16 granule (8 f32)
  const int bx = blockIdx.x;
  const float a = __expf(-2.0f * lsp[0]);
  const float* zrow = z + ((size_t)bx * 256 + n_st) * D + g_st * 8;

  // issue chunk-0 z loads first
  float4 zr0 = *(const float4*)(zrow);
  float4 zr1 = *(const float4*)(zrow + 4);

  // resident e A-fragments (16 KB per wave, loaded once)
  short8 A[16];
#pragma unroll
  for (int s = 0; s < 16; ++s)
    A[s] = *(const short8*)(eimg + wid * 16384 + s * 1024 + lane * 16);

  auto COMMIT = [&](int buf, float4 x0, float4 x1) {
    float sq = x0.x * x0.x + x0.y * x0.y + x0.z * x0.z + x0.w * x0.w +
               x1.x * x1.x + x1.y * x1.y + x1.z * x1.z + x1.w * x1.w;
    sq += shflx(sq, 1); sq += shflx(sq, 2); sq += shflx(sq, 4);
    sq += shflx(sq, 8); sq += shflx(sq, 16);      // 32 threads per row
    uint4 pk;
    pk.x = f2bf(x0.x) | (f2bf(x0.y) << 16);
    pk.y = f2bf(x0.z) | (f2bf(x0.w) << 16);
    pk.z = f2bf(x1.x) | (f2bf(x1.y) << 16);
    pk.w = f2bf(x1.z) | (f2bf(x1.w) << 16);
    // phys granule = g ^ n : conflict-free writes AND reads
    *(uint4*)(&zbuf[buf][0] + n_st * 512 + ((g_st ^ n_st) * 16)) = pk;
    if ((tid & 31) == 0) ztm[buf][n_st] = -0.5f * a * sq;
  };

  COMMIT(0, zr0, zr1);
  __syncthreads();

  float mx = -1e30f;        // shared per-lane running max (scores <= 0)
  float sm[16];
#pragma unroll
  for (int r = 0; r < 16; ++r) sm[r] = 0.0f;

  for (int c = 0; c < 8; ++c) {
    const int cur = c & 1;
    if (c < 7) {  // issue next chunk's z loads; land during MFMA+epilogue
      const float* src = zrow + (size_t)(c + 1) * 32 * D;
      zr0 = *(const float4*)(src);
      zr1 = *(const float4*)(src + 4);
    }

    f32x16 acc;
#pragma unroll
    for (int i = 0; i < 16; ++i) acc[i] = 0.0f;
#pragma unroll
    for (int s = 0; s < 16; ++s) {
      // B frag: z-row n = l31, granule 2s+hi (XOR-swizzled)
      short8 B = *(const short8*)(&zbuf[cur][0] + l31 * 512 +
                                  (((2 * s + hi) ^ l31) * 16));
      acc = __builtin_amdgcn_mfma_f32_32x32x16_bf16(A[s], B, acc, 0, 0, 0);
    }

    // online update: lane = z-row (bx*256 + c*32 + l31), regs = 16 e-cols
    const float zt = ztm[cur][l31];
    float vmax = acc[0];
#pragma unroll
    for (int r = 1; r < 16; ++r) vmax = fmaxf(vmax, acc[r]);
    vmax += zt;
    const float nm = fmaxf(mx, vmax);
    const float sc = __expf(mx - nm);     // 0 on first chunk (mx = -1e30)
    const float tz = zt - nm;
#pragma unroll
    for (int r = 0; r < 16; ++r) sm[r] = sm[r] * sc + __expf(acc[r] + tz);
    mx = nm;

    if (c < 7) COMMIT(cur ^ 1, zr0, zr1);
    __syncthreads();  // commit visible; all reads of buf[cur] done
  }

  // final cross-lane merge over the 32 z-row slots (masks stay in 32-half)
  float MX = mx;
  MX = fmaxf(MX, shflx(MX, 1));  MX = fmaxf(MX, shflx(MX, 2));
  MX = fmaxf(MX, shflx(MX, 4));  MX = fmaxf(MX, shflx(MX, 8));
  MX = fmaxf(MX, shflx(MX, 16));
  const float sc = __expf(mx - MX);
#pragma unroll
  for (int r = 0; r < 16; ++r) {
    float t = sm[r] * sc;
    t += shflx(t, 1); t += shflx(t, 2); t += shflx(t, 4);
    t += shflx(t, 8); t += shflx(t, 16);
    sm[r] = t;
  }
  if (l31 == 0) {  // lanes 0 (hi=0) and 32 (hi=1) store their 16 cols
#pragma unroll
    for (int r = 0; r < 16; ++r) {
      const int col = wid * 32 + (r & 3) + 8 * (r >> 2) + 4 * hi;
      wmax[(size_t)bx * 512 + col] = MX;
      wsum[(size_t)bx * 512 + col] = sm[r];
    }
  }
}

// ---- merge the 2 main-blocks of each 512-row b-block, add eterm, reduce ----
__global__ void merge_b(const float* __restrict__ wmax, const float* __restrict__ wsum,
                        const float* __restrict__ eterm, float* __restrict__ partial) {
  __shared__ float sh[512];
  const int b = blockIdx.x, t = threadIdx.x;
  float m0 = wmax[(size_t)(2 * b) * 512 + t];
  float m1 = wmax[(size_t)(2 * b + 1) * 512 + t];
  float s0 = wsum[(size_t)(2 * b) * 512 + t];
  float s1 = wsum[(size_t)(2 * b + 1) * 512 + t];
  float nm = fmaxf(m0, m1);
  float s = s0 * __expf(m0 - nm) + s1 * __expf(m1 - nm);
  sh[t] = nm + logf(s) + eterm[t];
  __syncthreads();
  for (int st = 256; st > 0; st >>= 1) {
    if (t < st) sh[t] += sh[t + st];
    __syncthreads();
  }
  if (t == 0) partial[b] = sh[0];
}

__global__ void final_k(const float* __restrict__ partial,
                        const float* __restrict__ lsp, float* __restrict__ out) {
  __shared__ float sh[128];
  const int t = threadIdx.x;
  sh[t] = partial[t];
  __syncthreads();
  for (int st = 64; st > 0; st >>= 1) {
    if (t < st) sh[t] += sh[t + st];
    __syncthreads();
  }
  if (t == 0) {
    float ls = lsp[0];
    out[0] = -sh[0] / 65536.0f + 128.0f * (2.0f * ls - 1.0f) + logf(512.0f);
  }
}

extern "C" void kernel_launch(void* const* d_in, const int* in_sizes, int n_in,
                              void* d_out, int out_size, void* d_ws, size_t ws_size,
                              hipStream_t stream) {
  const float* z   = (const float*)d_in[0];
  const float* e   = (const float*)d_in[1];
  const float* lsp = (const float*)d_in[2];
  float* out = (float*)d_out;
  char* ws = (char*)d_ws;
  char*  eimg    = ws + WS_EIMG;
  float* eterm   = (float*)(ws + WS_ETERM);
  float* wmax    = (float*)(ws + WS_WMAX);
  float* wsum    = (float*)(ws + WS_WSUM);
  float* partial = (float*)(ws + WS_PART);

  prep_e<<<dim3(16), dim3(256), 0, stream>>>(e, lsp, eimg, eterm);
  lse_main<<<dim3(256), dim3(1024), 0, stream>>>(z, eimg, lsp, wmax, wsum);
  merge_b<<<dim3(128), dim3(512), 0, stream>>>(wmax, wsum, eterm, partial);
  final_k<<<dim3(1), dim3(128), 0, stream>>>(partial, lsp, out);
}